// Round 10
// baseline (300.609 us; speedup 1.0000x reference)
//
#include <hip/hip_runtime.h>
#include <hip/hip_bf16.h>

#define B_ 64
#define S_ 1024
#define H_ 1024
#define M_ (B_*S_)   // 65536 rows of the big GEMM

typedef __attribute__((ext_vector_type(8))) short short8;
typedef __attribute__((ext_vector_type(4))) float f32x4;
typedef __attribute__((ext_vector_type(16))) float f32x16;

__device__ __forceinline__ unsigned short f2bf(float f) {
    union { float f; unsigned u; } c; c.f = f;
    unsigned u = c.u;
    unsigned r = (u + 0x7fffu + ((u >> 16) & 1u)) >> 16;  // RTNE, finite inputs
    return (unsigned short)r;
}

__device__ __forceinline__ float bf2f(unsigned short h) {
    union { unsigned u; float f; } c; c.u = ((unsigned)h) << 16;
    return c.f;
}

__device__ __forceinline__ float tanh_fast(float x) {
    float t = __expf(2.0f * x);
    return 1.0f - 2.0f * __builtin_amdgcn_rcpf(t + 1.0f);  // inf-safe
}

// async global->LDS, 16B per lane. LDS dest = wave-uniform base + lane*16.
__device__ __forceinline__ void gll16(const unsigned short* g, unsigned short* l) {
    auto* gp = (const __attribute__((address_space(1))) unsigned short*)(g);
    auto* lp = (__attribute__((address_space(3))) unsigned short*)(l);
    __builtin_amdgcn_global_load_lds(gp, lp, 16, 0, 0);
}

// ---------------------------------------------------------------------------
// K0: f32 -> bf16 conversion for BOTH enc and Wh in one launch
// ---------------------------------------------------------------------------
__global__ void cvt2_bf16_kernel(const float* __restrict__ s0,
                                 unsigned short* __restrict__ d0, int n0,
                                 const float* __restrict__ s1,
                                 unsigned short* __restrict__ d1, int n1) {
    int idx = blockIdx.x * blockDim.x + threadIdx.x;
    int stride = gridDim.x * blockDim.x;
    for (int i = idx; i < n0 + n1; i += stride) {
        const float4* s4;
        unsigned short* dp;
        if (i < n0) { s4 = (const float4*)s0 + (size_t)i * 2; dp = d0 + (size_t)i * 8; }
        else { int j = i - n0; s4 = (const float4*)s1 + (size_t)j * 2; dp = d1 + (size_t)j * 8; }
        float4 a = s4[0], b = s4[1];
        short8 o;
        o[0] = f2bf(a.x); o[1] = f2bf(a.y); o[2] = f2bf(a.z); o[3] = f2bf(a.w);
        o[4] = f2bf(b.x); o[5] = f2bf(b.y); o[6] = f2bf(b.z); o[7] = f2bf(b.w);
        *(short8*)dp = o;
    }
}

// ---------------------------------------------------------------------------
// K1a: proj_s split-K partials. grid = 256 = (kt 16) x (hs 16), 256 thr.
// ---------------------------------------------------------------------------
__global__ void proj_s_part_kernel(const float* __restrict__ dec,
                                   const float* __restrict__ Ws,
                                   float* __restrict__ part) {
    __shared__ float wss[64][68];
    const int kt = blockIdx.x & 15, hs = blockIdx.x >> 4;
    const int k0 = kt * 64, h0 = hs * 64;
    const int t = threadIdx.x;

    {
        const int r = t >> 2, c = (t & 3) * 16;
        const float4* src = (const float4*)(Ws + (size_t)(k0 + r) * H_ + h0 + c);
        float4 v0 = src[0], v1 = src[1], v2 = src[2], v3 = src[3];
        *(float4*)&wss[r][c + 0]  = v0;
        *(float4*)&wss[r][c + 4]  = v1;
        *(float4*)&wss[r][c + 8]  = v2;
        *(float4*)&wss[r][c + 12] = v3;
    }
    const int b = t >> 2, kq = t & 3;
    float4 dreg[16];
    const float4* dsrc = (const float4*)(dec + (size_t)b * H_ + h0);
#pragma unroll
    for (int i = 0; i < 16; ++i) dreg[i] = dsrc[i];
    __syncthreads();

    float acc[16] = {};
#pragma unroll
    for (int h4 = 0; h4 < 16; ++h4) {
        float4 d = dreg[h4];
#pragma unroll
        for (int j = 0; j < 16; ++j) {
            float4 wv = *(const float4*)&wss[kq + 4 * j][h4 * 4];
            acc[j] = fmaf(d.x, wv.x, acc[j]);
            acc[j] = fmaf(d.y, wv.y, acc[j]);
            acc[j] = fmaf(d.z, wv.z, acc[j]);
            acc[j] = fmaf(d.w, wv.w, acc[j]);
        }
    }
#pragma unroll
    for (int j = 0; j < 16; ++j)
        part[(size_t)hs * M_ + b * H_ + k0 + kq + 4 * j] = acc[j];
}

__global__ void proj_red_kernel(const float* __restrict__ part,
                                float* __restrict__ proj_s) {
    int i = blockIdx.x * 256 + threadIdx.x;
    float s = 0.0f;
#pragma unroll
    for (int p = 0; p < 16; ++p) s += part[(size_t)p * M_ + i];
    proj_s[i] = s;
}

// ---------------------------------------------------------------------------
// K2: 256x256 tile, BK=64, 8 waves (2Mx4N), 2x64KB LDS dbuf.
// R8-h2 PROVEN sync skeleton (identical STG stream + vmcnt ledger), MFMA
// shape switched to 32x32x16 (half the instructions, 15% higher rate).
// Per wave: 128x64 out = 4 m-frags x 2 n-frags of 32x32, acc f32x16[4][2].
// half1: mf0,1 (rows q0/q2) x both nf x ks0-3 -> 16 MFMA; needs {B all, Aq0,Aq2}
// half2: mf2,3 (rows q1/q3) -> 16 MFMA; needs {Aq1,Aq3}
// Stage for s+1: half1 issues B0..B3; half2 issues Aq0,Aq2,Aq1,Aq3.
// Waits: mid vmcnt(4) (retires Aq1,q3 of s; 4 B-stages fly); boundary vmcnt(2)
// (retires the 6 half1(s+1) needs; Aq1,q3(s+1) fly). Last tile: mid vmcnt(0).
// ---------------------------------------------------------------------------
__global__ void __launch_bounds__(512)
fused_scores_m32_kernel(const unsigned short* __restrict__ encb,
                        const unsigned short* __restrict__ Whb,
                        const float* __restrict__ proj_s,
                        const float* __restrict__ v,
                        float* __restrict__ scores_part) {
    __shared__ __align__(16) unsigned short Lsh[65536];  // 128KB: 2 x (A 32KB + B 32KB)

    // XCD swizzle: 1024 blocks, 8 XCDs -> each XCD gets 128 consecutive
    const int bx0 = blockIdx.x;
    const int bx = (bx0 & 7) * 128 + (bx0 >> 3);
    const int nt = bx & 3;    // 4 N-tiles of 256
    const int mt = bx >> 2;   // 256 M-tiles of 256
    const int t = threadIdx.x;
    const int wid = t >> 6, lane = t & 63;
    const int wr = wid >> 2, wc = wid & 3;       // 2M x 4N wave grid
    const int l31 = lane & 31, hi = lane >> 5;

    f32x16 acc[4][2] = {};

    // staging: gload g covers rows g*64..+63, one K-tile's 64 cols (128B rows).
    const int srow = t >> 3;                 // 0..63
    const int sgran = (t & 7) ^ (srow & 7);  // pre-swizzled source granule
    const unsigned short* gA = encb + (size_t)(mt * 256 + srow) * H_ + sgran * 8;
    const unsigned short* gB = Whb  + (size_t)(nt * 256 + srow) * H_ + sgran * 8;

    // bb: buffer 0/1; op: 0=A,1=B; g: row-quarter 0..3; kt: K-tile
#define STG(bb, op, g, kt) \
    gll16(((op) ? gB : gA) + (size_t)(g) * 64 * H_ + (kt) * 64, \
          Lsh + (bb) * 32768 + (op) * 16384 + (g) * 4096 + wid * 512)

    // fragment halfword offsets: frag (mf, ks): row = wr*128+mf*32+l31,
    // granule = (ks*2+hi) ^ (row&7). B symmetric (+16384, wc*64+nf*32+l31).
    int aoff[4][4], boff[2][4];
#pragma unroll
    for (int mf = 0; mf < 4; ++mf) {
        int row = wr * 128 + mf * 32 + l31;
#pragma unroll
        for (int ks = 0; ks < 4; ++ks)
            aoff[mf][ks] = row * 64 + (((ks * 2 + hi) ^ (row & 7))) * 8;
    }
#pragma unroll
    for (int nf = 0; nf < 2; ++nf) {
        int row = wc * 64 + nf * 32 + l31;
#pragma unroll
        for (int ks = 0; ks < 4; ++ks)
            boff[nf][ks] = 16384 + row * 64 + (((ks * 2 + hi) ^ (row & 7))) * 8;
    }

    // ---- prologue: stage tile 0 fully into buf0 (one-time full drain) ----
    STG(0,1,0,0); STG(0,1,1,0); STG(0,1,2,0); STG(0,1,3,0);
    STG(0,0,0,0); STG(0,0,1,0); STG(0,0,2,0); STG(0,0,3,0);
    asm volatile("s_waitcnt vmcnt(0)" ::: "memory");
    __builtin_amdgcn_sched_barrier(0);
    __builtin_amdgcn_s_barrier();

    int buf = 0;
    for (int s = 0; s < 16; ++s) {
        const int hb = buf * 32768;
        const int sb = buf ^ 1;
        const bool st = (s < 15);
        short8 af[2][4], bk[2][4];

        // ======== HALF 1: mf0,1 x nf0,1 x ks0-3 (all tile-start resident) ====
#pragma unroll
        for (int nf = 0; nf < 2; ++nf)
#pragma unroll
            for (int ks = 0; ks < 4; ++ks)
                bk[nf][ks] = *(const short8*)&Lsh[hb + boff[nf][ks]];
#pragma unroll
        for (int mf = 0; mf < 2; ++mf)
#pragma unroll
            for (int ks = 0; ks < 4; ++ks)
                af[mf][ks] = *(const short8*)&Lsh[hb + aoff[mf][ks]];
        if (st) { STG(sb,1,0,s+1); STG(sb,1,1,s+1); STG(sb,1,2,s+1); STG(sb,1,3,s+1); }
        __builtin_amdgcn_s_setprio(1);
#pragma unroll
        for (int mf = 0; mf < 2; ++mf)
#pragma unroll
            for (int nf = 0; nf < 2; ++nf)
#pragma unroll
                for (int ks = 0; ks < 4; ++ks)
                    acc[mf][nf] = __builtin_amdgcn_mfma_f32_32x32x16_bf16(
                        af[mf][ks], bk[nf][ks], acc[mf][nf], 0, 0, 0);
        __builtin_amdgcn_s_setprio(0);

        // ---- mid-tile sync: retire A q1,q3 of THIS tile (keep 4 B-stages flying)
        if (st) { asm volatile("s_waitcnt vmcnt(4)" ::: "memory"); }
        else    { asm volatile("s_waitcnt vmcnt(0)" ::: "memory"); }
        __builtin_amdgcn_sched_barrier(0);
        __builtin_amdgcn_s_barrier();

        // ======== HALF 2: mf2,3 ====
#pragma unroll
        for (int mf = 0; mf < 2; ++mf)
#pragma unroll
            for (int ks = 0; ks < 4; ++ks)
                af[mf][ks] = *(const short8*)&Lsh[hb + aoff[2 + mf][ks]];
        if (st) { STG(sb,0,0,s+1); STG(sb,0,2,s+1); STG(sb,0,1,s+1); STG(sb,0,3,s+1); }
        __builtin_amdgcn_s_setprio(1);
#pragma unroll
        for (int mf = 0; mf < 2; ++mf)
#pragma unroll
            for (int nf = 0; nf < 2; ++nf)
#pragma unroll
                for (int ks = 0; ks < 4; ++ks)
                    acc[2 + mf][nf] = __builtin_amdgcn_mfma_f32_32x32x16_bf16(
                        af[mf][ks], bk[nf][ks], acc[2 + mf][nf], 0, 0, 0);
        __builtin_amdgcn_s_setprio(0);

        // ---- boundary: retire the 6 loads half-1(s+1) needs; keep A q1,q3 flying
        if (st) { asm volatile("s_waitcnt vmcnt(2)" ::: "memory"); }
        __builtin_amdgcn_sched_barrier(0);
        __builtin_amdgcn_s_barrier();
        buf ^= 1;
    }
#undef STG

    // ---- epilogue: tanh(acc + proj_s) . v, reduce over the 32 cols/frag ----
    // C layout (32x32): col = lane&31, row = (reg&3) + 8*(reg>>2) + 4*hi.
    const int b = mt >> 2;   // 4 M-tiles per batch row (256 | 1024)
    float vv[2], ps[2];
#pragma unroll
    for (int nf = 0; nf < 2; ++nf) {
        int col = nt * 256 + wc * 64 + nf * 32 + l31;
        vv[nf] = v[col];
        ps[nf] = proj_s[b * H_ + col];
    }
    float* sums = (float*)Lsh;   // reuse: [256 rows][4 wc] f32 = 4KB
#pragma unroll
    for (int mf = 0; mf < 4; ++mf) {
#pragma unroll
        for (int j = 0; j < 16; ++j) {
            float s = fmaf(tanh_fast(acc[mf][0][j] + ps[0]), vv[0],
                           tanh_fast(acc[mf][1][j] + ps[1]) * vv[1]);
            // sum over 32 cols: butterfly within each 32-lane half
            s += __shfl_xor(s, 1, 64);
            s += __shfl_xor(s, 2, 64);
            s += __shfl_xor(s, 4, 64);
            s += __shfl_xor(s, 8, 64);
            s += __shfl_xor(s, 16, 64);
            if (l31 == 0) {
                int row = wr * 128 + mf * 32 + (j & 3) + 8 * (j >> 2) + 4 * hi;
                sums[row * 4 + wc] = s;
            }
        }
    }
    __syncthreads();
    if (t < 256) {
        float r = sums[t * 4 + 0] + sums[t * 4 + 1] + sums[t * 4 + 2] + sums[t * 4 + 3];
        scores_part[(size_t)nt * M_ + mt * 256 + t] = r;
    }
}

// ---------------------------------------------------------------------------
// K2 fallback: f32-input version (reg-staged conversion), 128x128, np=8.
// ---------------------------------------------------------------------------
__global__ void fused_scores_kernel(const float* __restrict__ enc,
                                    const float* __restrict__ Wh,
                                    const float* __restrict__ proj_s,
                                    const float* __restrict__ v,
                                    float* __restrict__ scores_part) {
    __shared__ __align__(16) unsigned short As[128][40];
    __shared__ __align__(16) unsigned short Bs[128][40];
    __shared__ float sums[128][2];

    const int bx = blockIdx.x;
    const int nt = bx & 7;
    const int mt = bx >> 3;
    const int t = threadIdx.x;
    const int w = t >> 6, lane = t & 63;
    const int wr = w >> 1, wc = w & 1;
    const int lrow = lane & 15, lgrp = lane >> 4;

    f32x4 acc[4][4] = {};

    const int srow = t >> 1;
    const int shalf = t & 1;
    const float* gA = enc + (size_t)(mt * 128 + srow) * H_ + shalf * 16;
    const float* gB = Wh  + (size_t)(nt * 128 + srow) * H_ + shalf * 16;
    unsigned short* lA = &As[srow][shalf * 16];
    unsigned short* lB = &Bs[srow][shalf * 16];

    for (int kt = 0; kt < H_ / 32; ++kt) {
        __syncthreads();
        const float4* a4 = (const float4*)(gA + kt * 32);
        const float4* b4 = (const float4*)(gB + kt * 32);
        union { unsigned short us[16]; uint4 q[2]; } pa, pb;
#pragma unroll
        for (int i = 0; i < 4; ++i) {
            float4 av = a4[i];
            float4 bv = b4[i];
            pa.us[i*4+0] = f2bf(av.x); pa.us[i*4+1] = f2bf(av.y);
            pa.us[i*4+2] = f2bf(av.z); pa.us[i*4+3] = f2bf(av.w);
            pb.us[i*4+0] = f2bf(bv.x); pb.us[i*4+1] = f2bf(bv.y);
            pb.us[i*4+2] = f2bf(bv.z); pb.us[i*4+3] = f2bf(bv.w);
        }
        *(uint4*)(lA)     = pa.q[0];
        *(uint4*)(lA + 8) = pa.q[1];
        *(uint4*)(lB)     = pb.q[0];
        *(uint4*)(lB + 8) = pb.q[1];
        __syncthreads();

        short8 af[4], bf[4];
#pragma unroll
        for (int m = 0; m < 4; ++m)
            af[m] = *(const short8*)&As[wr * 64 + m * 16 + lrow][lgrp * 8];
#pragma unroll
        for (int n = 0; n < 4; ++n)
            bf[n] = *(const short8*)&Bs[wc * 64 + n * 16 + lrow][lgrp * 8];
#pragma unroll
        for (int m = 0; m < 4; ++m)
#pragma unroll
            for (int n = 0; n < 4; ++n)
                acc[m][n] = __builtin_amdgcn_mfma_f32_16x16x32_bf16(af[m], bf[n], acc[m][n], 0, 0, 0);
    }

    const int b = mt >> 3;
    float vv[4], ps[4];
#pragma unroll
    for (int n = 0; n < 4; ++n) {
        int col = nt * 128 + wc * 64 + n * 16 + lrow;
        vv[n] = v[col];
        ps[n] = proj_s[b * H_ + col];
    }
    float rs[4][4];
#pragma unroll
    for (int m = 0; m < 4; ++m) {
#pragma unroll
        for (int j = 0; j < 4; ++j) {
            float s = 0.0f;
#pragma unroll
            for (int n = 0; n < 4; ++n)
                s = fmaf(tanh_fast(acc[m][n][j] + ps[n]), vv[n], s);
            s += __shfl_xor(s, 1, 64);
            s += __shfl_xor(s, 2, 64);
            s += __shfl_xor(s, 4, 64);
            s += __shfl_xor(s, 8, 64);
            rs[m][j] = s;
        }
    }
    if (lrow == 0) {
#pragma unroll
        for (int m = 0; m < 4; ++m)
#pragma unroll
            for (int j = 0; j < 4; ++j)
                sums[wr * 64 + m * 16 + lgrp * 4 + j][wc] = rs[m][j];
    }
    __syncthreads();
    if (t < 128)
        scores_part[(size_t)nt * M_ + mt * 128 + t] = sums[t][0] + sums[t][1];
}

// ---------------------------------------------------------------------------
// K3: softmax over S per batch row (np N-tile partials)
// ---------------------------------------------------------------------------
__global__ void softmax_kernel(const float* __restrict__ scores_part,
                               const int* __restrict__ mask,
                               float* __restrict__ weights, int np) {
    const int b = blockIdx.x, t = threadIdx.x;
    __shared__ float red[8];
    float sc[4];
#pragma unroll
    for (int i = 0; i < 4; ++i) {
        int s = t + i * 256;
        float x = 0.0f;
        for (int p = 0; p < np; ++p)
            x += scores_part[(size_t)p * M_ + b * S_ + s];
        if (mask[b * S_ + s] == 0) x = -INFINITY;
        sc[i] = x;
    }
    float mx = fmaxf(fmaxf(sc[0], sc[1]), fmaxf(sc[2], sc[3]));
#pragma unroll
    for (int m = 32; m >= 1; m >>= 1) mx = fmaxf(mx, __shfl_xor(mx, m, 64));
    if ((t & 63) == 0) red[t >> 6] = mx;
    __syncthreads();
    mx = fmaxf(fmaxf(red[0], red[1]), fmaxf(red[2], red[3]));

    float e[4]; float sum = 0.0f;
#pragma unroll
    for (int i = 0; i < 4; ++i) { e[i] = __expf(sc[i] - mx); sum += e[i]; }
#pragma unroll
    for (int m = 32; m >= 1; m >>= 1) sum += __shfl_xor(sum, m, 64);
    if ((t & 63) == 0) red[4 + (t >> 6)] = sum;
    __syncthreads();
    sum = red[4] + red[5] + red[6] + red[7];
    float inv = 1.0f / sum;
#pragma unroll
    for (int i = 0; i < 4; ++i)
        weights[b * S_ + t + i * 256] = e[i] * inv;
}

// ---------------------------------------------------------------------------
// K4 fast: context partials reading bf16 enc. grid = 1024 = b(64) x sc(16),
// 128 threads; thread owns 8 h over 64 s-rows.
// ---------------------------------------------------------------------------
__global__ void context_part_bf16_kernel(const unsigned short* __restrict__ encb,
                                         const float* __restrict__ weights,
                                         float* __restrict__ ctx_part) {
    const int b = blockIdx.x >> 4;
    const int sc = blockIdx.x & 15;
    const int t = threadIdx.x;   // 0..127
    __shared__ float wv[64];
    if (t < 64) wv[t] = weights[b * S_ + sc * 64 + t];
    __syncthreads();
    const short8* e8 = (const short8*)(encb + (size_t)(b * S_ + sc * 64) * H_) + t;
    float a[8] = {};
#pragma unroll 4
    for (int i = 0; i < 64; ++i) {
        short8 ev = e8[(size_t)i * 128];
        float w = wv[i];
#pragma unroll
        for (int j = 0; j < 8; ++j)
            a[j] = fmaf(w, bf2f((unsigned short)ev[j]), a[j]);
    }
    float* dst = ctx_part + (size_t)sc * M_ + b * H_ + t * 8;
    float4 o0; o0.x = a[0]; o0.y = a[1]; o0.z = a[2]; o0.w = a[3];
    float4 o1; o1.x = a[4]; o1.y = a[5]; o1.z = a[6]; o1.w = a[7];
    *(float4*)dst = o0;
    *(float4*)(dst + 4) = o1;
}

__global__ void context_part_kernel(const float* __restrict__ enc,
                                    const float* __restrict__ weights,
                                    float* __restrict__ ctx_part) {
    const int b = blockIdx.x >> 4;
    const int sc = blockIdx.x & 15;
    const int t = threadIdx.x;
    __shared__ float wv[64];
    if (t < 64) wv[t] = weights[b * S_ + sc * 64 + t];
    __syncthreads();
    const float4* e4 = (const float4*)(enc + (size_t)(b * S_ + sc * 64) * H_) + t;
    float ax = 0.f, ay = 0.f, az = 0.f, aw = 0.f;
#pragma unroll 4
    for (int i = 0; i < 64; ++i) {
        float4 ev = e4[i * 256];
        float wgt = wv[i];
        ax = fmaf(wgt, ev.x, ax);
        ay = fmaf(wgt, ev.y, ay);
        az = fmaf(wgt, ev.z, az);
        aw = fmaf(wgt, ev.w, aw);
    }
    float4 o; o.x = ax; o.y = ay; o.z = az; o.w = aw;
    *((float4*)(ctx_part + (size_t)sc * M_ + b * H_) + t) = o;
}

__global__ void ctx_reduce_kernel(const float* __restrict__ ctx_part,
                                  float* __restrict__ ctx, int np) {
    int idx = blockIdx.x * 256 + threadIdx.x;
    float s = 0.0f;
    for (int p = 0; p < np; ++p) s += ctx_part[(size_t)p * M_ + idx];
    ctx[idx] = s;
}

extern "C" void kernel_launch(void* const* d_in, const int* in_sizes, int n_in,
                              void* d_out, int out_size, void* d_ws, size_t ws_size,
                              hipStream_t stream) {
    const float* dec  = (const float*)d_in[0];   // [B,H]
    const float* enc  = (const float*)d_in[1];   // [B,S,H]
    const int*   mask = (const int*)d_in[2];     // [B,S]
    const float* Ws   = (const float*)d_in[3];   // [H,H]
    const float* Wh   = (const float*)d_in[4];   // [H,H]
    const float* v    = (const float*)d_in[5];   // [H]

    float* out = (float*)d_out;          // [0:65536] context, [65536:131072] weights

    float* proj_s      = (float*)d_ws;                   // 65536 f32
    float* proj_part   = proj_s + M_;                    // 16 * 65536 f32
    float* scores_part = proj_part + 16 * (size_t)M_;    // 8 * 65536 f32
    float* ctx_part    = scores_part + 8 * (size_t)M_;   // 32 * 65536 f32
    unsigned short* encb = (unsigned short*)(ctx_part + 32 * (size_t)M_);  // 64M bf16
    unsigned short* Whb  = encb + (size_t)B_ * S_ * H_;                    // 1M bf16

    const size_t need_small = 4ull * (1 + 16 + 8 + 32) * M_;
    const size_t need_big   = need_small + 2ull * ((size_t)B_ * S_ * H_ + (size_t)H_ * H_);

    proj_s_part_kernel<<<256, 256, 0, stream>>>(dec, Ws, proj_part);
    proj_red_kernel<<<256, 256, 0, stream>>>(proj_part, proj_s);

    if (ws_size >= need_big) {
        cvt2_bf16_kernel<<<2048, 256, 0, stream>>>(enc, encb, B_ * S_ * H_ / 8,
                                                   Wh, Whb, H_ * H_ / 8);
        fused_scores_m32_kernel<<<1024, 512, 0, stream>>>(encb, Whb, proj_s, v, scores_part);
        softmax_kernel<<<64, 256, 0, stream>>>(scores_part, mask, out + M_, 4);
        context_part_bf16_kernel<<<1024, 128, 0, stream>>>(encb, out + M_, ctx_part);
        ctx_reduce_kernel<<<256, 256, 0, stream>>>(ctx_part, out, 16);
    } else {
        fused_scores_kernel<<<4096, 256, 0, stream>>>(enc, Wh, proj_s, v, scores_part);
        softmax_kernel<<<64, 256, 0, stream>>>(scores_part, mask, out + M_, 8);
        context_part_kernel<<<1024, 256, 0, stream>>>(enc, out + M_, ctx_part);
        ctx_reduce_kernel<<<256, 256, 0, stream>>>(ctx_part, out, 16);
    }
}

// Round 11
// 257.994 us; speedup vs baseline: 1.1652x; 1.1652x over previous
//
#include <hip/hip_runtime.h>
#include <hip/hip_bf16.h>

#define B_ 64
#define S_ 1024
#define H_ 1024
#define M_ (B_*S_)   // 65536 rows of the big GEMM

typedef __attribute__((ext_vector_type(8))) short short8;
typedef __attribute__((ext_vector_type(4))) float f32x4;

__device__ __forceinline__ unsigned short f2bf(float f) {
    union { float f; unsigned u; } c; c.f = f;
    unsigned u = c.u;
    unsigned r = (u + 0x7fffu + ((u >> 16) & 1u)) >> 16;  // RTNE, finite inputs
    return (unsigned short)r;
}

__device__ __forceinline__ float bf2f(unsigned short h) {
    union { unsigned u; float f; } c; c.u = ((unsigned)h) << 16;
    return c.f;
}

__device__ __forceinline__ float tanh_fast(float x) {
    float t = __expf(2.0f * x);
    return 1.0f - 2.0f * __builtin_amdgcn_rcpf(t + 1.0f);  // inf-safe
}

// async global->LDS, 16B per lane. LDS dest = wave-uniform base + lane*16.
__device__ __forceinline__ void gll16(const unsigned short* g, unsigned short* l) {
    auto* gp = (const __attribute__((address_space(1))) unsigned short*)(g);
    auto* lp = (__attribute__((address_space(3))) unsigned short*)(l);
    __builtin_amdgcn_global_load_lds(gp, lp, 16, 0, 0);
}

// ---------------------------------------------------------------------------
// K0: f32 -> bf16 conversion for BOTH enc and Wh in one launch
// ---------------------------------------------------------------------------
__global__ void cvt2_bf16_kernel(const float* __restrict__ s0,
                                 unsigned short* __restrict__ d0, int n0,
                                 const float* __restrict__ s1,
                                 unsigned short* __restrict__ d1, int n1) {
    int idx = blockIdx.x * blockDim.x + threadIdx.x;
    int stride = gridDim.x * blockDim.x;
    for (int i = idx; i < n0 + n1; i += stride) {
        const float4* s4;
        unsigned short* dp;
        if (i < n0) { s4 = (const float4*)s0 + (size_t)i * 2; dp = d0 + (size_t)i * 8; }
        else { int j = i - n0; s4 = (const float4*)s1 + (size_t)j * 2; dp = d1 + (size_t)j * 8; }
        float4 a = s4[0], b = s4[1];
        short8 o;
        o[0] = f2bf(a.x); o[1] = f2bf(a.y); o[2] = f2bf(a.z); o[3] = f2bf(a.w);
        o[4] = f2bf(b.x); o[5] = f2bf(b.y); o[6] = f2bf(b.z); o[7] = f2bf(b.w);
        *(short8*)dp = o;
    }
}

// ---------------------------------------------------------------------------
// K1a: proj_s split-K partials. grid = 256 = (kt 16) x (hs 16), 256 thr.
// ---------------------------------------------------------------------------
__global__ void proj_s_part_kernel(const float* __restrict__ dec,
                                   const float* __restrict__ Ws,
                                   float* __restrict__ part) {
    __shared__ float wss[64][68];
    const int kt = blockIdx.x & 15, hs = blockIdx.x >> 4;
    const int k0 = kt * 64, h0 = hs * 64;
    const int t = threadIdx.x;

    {
        const int r = t >> 2, c = (t & 3) * 16;
        const float4* src = (const float4*)(Ws + (size_t)(k0 + r) * H_ + h0 + c);
        float4 v0 = src[0], v1 = src[1], v2 = src[2], v3 = src[3];
        *(float4*)&wss[r][c + 0]  = v0;
        *(float4*)&wss[r][c + 4]  = v1;
        *(float4*)&wss[r][c + 8]  = v2;
        *(float4*)&wss[r][c + 12] = v3;
    }
    const int b = t >> 2, kq = t & 3;
    float4 dreg[16];
    const float4* dsrc = (const float4*)(dec + (size_t)b * H_ + h0);
#pragma unroll
    for (int i = 0; i < 16; ++i) dreg[i] = dsrc[i];
    __syncthreads();

    float acc[16] = {};
#pragma unroll
    for (int h4 = 0; h4 < 16; ++h4) {
        float4 d = dreg[h4];
#pragma unroll
        for (int j = 0; j < 16; ++j) {
            float4 wv = *(const float4*)&wss[kq + 4 * j][h4 * 4];
            acc[j] = fmaf(d.x, wv.x, acc[j]);
            acc[j] = fmaf(d.y, wv.y, acc[j]);
            acc[j] = fmaf(d.z, wv.z, acc[j]);
            acc[j] = fmaf(d.w, wv.w, acc[j]);
        }
    }
#pragma unroll
    for (int j = 0; j < 16; ++j)
        part[(size_t)hs * M_ + b * H_ + k0 + kq + 4 * j] = acc[j];
}

__global__ void proj_red_kernel(const float* __restrict__ part,
                                float* __restrict__ proj_s) {
    int i = blockIdx.x * 256 + threadIdx.x;
    float s = 0.0f;
#pragma unroll
    for (int p = 0; p < 16; ++p) s += part[(size_t)p * M_ + i];
    proj_s[i] = s;
}

// ---------------------------------------------------------------------------
// K2: 256x256 tile, BK=64, 8 waves (2Mx4N), 2x64KB LDS dbuf.
// R7-proven BARRIER-MINIMAL body: 4 straight-line phases {ds_read ||
// stage-issue || MFMA}, only 2 {counted vmcnt + s_barrier} per K-tile.
// 16x16x32 MFMA, granule-XOR swizzle (measured conflict-free, MfmaUtil 39%).
// Waits: mid vmcnt(2) retires Aq1,q3 of this tile; boundary vmcnt(2) retires
// the 6 loads next ph0 needs. Last tile: mid vmcnt(0) (R5 race lesson).
// ---------------------------------------------------------------------------
__global__ void __launch_bounds__(512)
fused_scores_p4_kernel(const unsigned short* __restrict__ encb,
                       const unsigned short* __restrict__ Whb,
                       const float* __restrict__ proj_s,
                       const float* __restrict__ v,
                       float* __restrict__ scores_part) {
    __shared__ __align__(16) unsigned short Lsh[65536];  // 128KB: 2 x (A 32KB + B 32KB)

    // XCD swizzle: 1024 blocks, 8 XCDs -> each XCD gets 128 consecutive
    const int bx0 = blockIdx.x;
    const int bx = (bx0 & 7) * 128 + (bx0 >> 3);
    const int nt = bx & 3;    // 4 N-tiles of 256
    const int mt = bx >> 2;   // 256 M-tiles of 256
    const int t = threadIdx.x;
    const int wid = t >> 6, lane = t & 63;
    const int wr = wid >> 2, wc = wid & 3;       // 2M x 4N wave grid
    const int lrow = lane & 15, lgrp = lane >> 4;

    f32x4 acc[8][4] = {};

    // staging: gload g covers rows g*64..+63, one K-tile's 64 cols (128B rows).
    const int srow = t >> 3;                 // 0..63
    const int sgran = (t & 7) ^ (srow & 7);  // pre-swizzled source granule
    const unsigned short* gA = encb + (size_t)(mt * 256 + srow) * H_ + sgran * 8;
    const unsigned short* gB = Whb  + (size_t)(nt * 256 + srow) * H_ + sgran * 8;

    // bb: buffer 0/1; op: 0=A,1=B; g: row-quarter 0..3; kt: K-tile
#define STG(bb, op, g, kt) \
    gll16(((op) ? gB : gA) + (size_t)(g) * 64 * H_ + (kt) * 64, \
          Lsh + (bb) * 32768 + (op) * 16384 + (g) * 4096 + wid * 512)

    // fragment halfword offsets (k-half 0); k-half 1 = offset ^ 32
    int aoff[8], boff[4];
#pragma unroll
    for (int m = 0; m < 8; ++m) {
        int row = wr * 128 + m * 16 + lrow;
        aoff[m] = row * 64 + (lgrp ^ (row & 7)) * 8;
    }
#pragma unroll
    for (int n = 0; n < 4; ++n) {
        int row = wc * 64 + n * 16 + lrow;
        boff[n] = 16384 + row * 64 + (lgrp ^ (row & 7)) * 8;
    }

    // ---- prologue: stage tile 0 fully into buf0 (one-time full drain) ----
    STG(0,1,0,0); STG(0,1,1,0); STG(0,1,2,0); STG(0,1,3,0);
    STG(0,0,0,0); STG(0,0,1,0); STG(0,0,2,0); STG(0,0,3,0);
    asm volatile("s_waitcnt vmcnt(0)" ::: "memory");
    __builtin_amdgcn_sched_barrier(0);
    __builtin_amdgcn_s_barrier();

    int buf = 0;
    for (int s = 0; s < 16; ++s) {
        const int hb = buf * 32768;
        const int sb = buf ^ 1;
        const bool st = (s < 15);
        short8 a0[4], a1[4], bk0[4], bk1[4];

        // ---- ph0: B@k0 + A m0-3 @k0 ; stage B0,B1 ; MFMA quadrant ----
#pragma unroll
        for (int n = 0; n < 4; ++n) bk0[n] = *(const short8*)&Lsh[hb + boff[n]];
#pragma unroll
        for (int m = 0; m < 4; ++m) a0[m] = *(const short8*)&Lsh[hb + aoff[m]];
        if (st) { STG(sb,1,0,s+1); STG(sb,1,1,s+1); }
        __builtin_amdgcn_s_setprio(1);
#pragma unroll
        for (int m = 0; m < 4; ++m)
#pragma unroll
            for (int n = 0; n < 4; ++n)
                acc[m][n] = __builtin_amdgcn_mfma_f32_16x16x32_bf16(a0[m], bk0[n], acc[m][n], 0, 0, 0);
        __builtin_amdgcn_s_setprio(0);

        // ---- mid-tile sync: retire Aq1,Aq3 of THIS tile before ph1 reads ----
        if (st) { asm volatile("s_waitcnt vmcnt(2)" ::: "memory"); }
        else    { asm volatile("s_waitcnt vmcnt(0)" ::: "memory"); }
        __builtin_amdgcn_sched_barrier(0);
        __builtin_amdgcn_s_barrier();

        // ---- ph1: A m4-7 @k0 + B@k1 ; stage B2,B3 ; MFMA ----
#pragma unroll
        for (int m = 0; m < 4; ++m) a1[m] = *(const short8*)&Lsh[hb + aoff[4 + m]];
#pragma unroll
        for (int n = 0; n < 4; ++n) bk1[n] = *(const short8*)&Lsh[hb + (boff[n] ^ 32)];
        if (st) { STG(sb,1,2,s+1); STG(sb,1,3,s+1); }
        __builtin_amdgcn_s_setprio(1);
#pragma unroll
        for (int m = 0; m < 4; ++m)
#pragma unroll
            for (int n = 0; n < 4; ++n)
                acc[4 + m][n] = __builtin_amdgcn_mfma_f32_16x16x32_bf16(a1[m], bk0[n], acc[4 + m][n], 0, 0, 0);
        __builtin_amdgcn_s_setprio(0);

        // ---- ph2: A m0-3 @k1 ; stage Aq0,Aq2 ; MFMA (B@k1 in regs) ----
#pragma unroll
        for (int m = 0; m < 4; ++m) a0[m] = *(const short8*)&Lsh[hb + (aoff[m] ^ 32)];
        if (st) { STG(sb,0,0,s+1); STG(sb,0,2,s+1); }
        __builtin_amdgcn_s_setprio(1);
#pragma unroll
        for (int m = 0; m < 4; ++m)
#pragma unroll
            for (int n = 0; n < 4; ++n)
                acc[m][n] = __builtin_amdgcn_mfma_f32_16x16x32_bf16(a0[m], bk1[n], acc[m][n], 0, 0, 0);
        __builtin_amdgcn_s_setprio(0);

        // ---- ph3: A m4-7 @k1 ; stage Aq1,Aq3 ; MFMA ----
#pragma unroll
        for (int m = 0; m < 4; ++m) a1[m] = *(const short8*)&Lsh[hb + (aoff[4 + m] ^ 32)];
        if (st) { STG(sb,0,1,s+1); STG(sb,0,3,s+1); }
        __builtin_amdgcn_s_setprio(1);
#pragma unroll
        for (int m = 0; m < 4; ++m)
#pragma unroll
            for (int n = 0; n < 4; ++n)
                acc[4 + m][n] = __builtin_amdgcn_mfma_f32_16x16x32_bf16(a1[m], bk1[n], acc[4 + m][n], 0, 0, 0);
        __builtin_amdgcn_s_setprio(0);

        // ---- boundary: retire the 6 loads ph0(s+1) needs; keep 2 in flight ----
        if (st) { asm volatile("s_waitcnt vmcnt(2)" ::: "memory"); }
        __builtin_amdgcn_sched_barrier(0);
        __builtin_amdgcn_s_barrier();
        buf ^= 1;
    }
#undef STG

    // ---- epilogue: tanh(acc + proj_s) . v, reduce over cols ----
    const int b = mt >> 2;   // 4 M-tiles per batch row (256 | 1024)
    float vv[4], ps[4];
#pragma unroll
    for (int n = 0; n < 4; ++n) {
        int col = nt * 256 + wc * 64 + n * 16 + lrow;
        vv[n] = v[col];
        ps[n] = proj_s[b * H_ + col];
    }
    float* sums = (float*)Lsh;   // reuse: [256 rows][4 wc] f32 = 4KB
#pragma unroll
    for (int m = 0; m < 8; ++m) {
#pragma unroll
        for (int j = 0; j < 4; ++j) {
            float s = 0.0f;
#pragma unroll
            for (int n = 0; n < 4; ++n)
                s = fmaf(tanh_fast(acc[m][n][j] + ps[n]), vv[n], s);
            s += __shfl_xor(s, 1, 64);
            s += __shfl_xor(s, 2, 64);
            s += __shfl_xor(s, 4, 64);
            s += __shfl_xor(s, 8, 64);
            if (lrow == 0)
                sums[(wr * 128 + m * 16 + lgrp * 4 + j) * 4 + wc] = s;
        }
    }
    __syncthreads();
    if (t < 256) {
        float r = sums[t * 4 + 0] + sums[t * 4 + 1] + sums[t * 4 + 2] + sums[t * 4 + 3];
        scores_part[(size_t)nt * M_ + mt * 256 + t] = r;
    }
}

// ---------------------------------------------------------------------------
// K2 fallback: f32-input version (reg-staged conversion), 128x128, np=8.
// ---------------------------------------------------------------------------
__global__ void fused_scores_kernel(const float* __restrict__ enc,
                                    const float* __restrict__ Wh,
                                    const float* __restrict__ proj_s,
                                    const float* __restrict__ v,
                                    float* __restrict__ scores_part) {
    __shared__ __align__(16) unsigned short As[128][40];
    __shared__ __align__(16) unsigned short Bs[128][40];
    __shared__ float sums[128][2];

    const int bx = blockIdx.x;
    const int nt = bx & 7;
    const int mt = bx >> 3;
    const int t = threadIdx.x;
    const int w = t >> 6, lane = t & 63;
    const int wr = w >> 1, wc = w & 1;
    const int lrow = lane & 15, lgrp = lane >> 4;

    f32x4 acc[4][4] = {};

    const int srow = t >> 1;
    const int shalf = t & 1;
    const float* gA = enc + (size_t)(mt * 128 + srow) * H_ + shalf * 16;
    const float* gB = Wh  + (size_t)(nt * 128 + srow) * H_ + shalf * 16;
    unsigned short* lA = &As[srow][shalf * 16];
    unsigned short* lB = &Bs[srow][shalf * 16];

    for (int kt = 0; kt < H_ / 32; ++kt) {
        __syncthreads();
        const float4* a4 = (const float4*)(gA + kt * 32);
        const float4* b4 = (const float4*)(gB + kt * 32);
        union { unsigned short us[16]; uint4 q[2]; } pa, pb;
#pragma unroll
        for (int i = 0; i < 4; ++i) {
            float4 av = a4[i];
            float4 bv = b4[i];
            pa.us[i*4+0] = f2bf(av.x); pa.us[i*4+1] = f2bf(av.y);
            pa.us[i*4+2] = f2bf(av.z); pa.us[i*4+3] = f2bf(av.w);
            pb.us[i*4+0] = f2bf(bv.x); pb.us[i*4+1] = f2bf(bv.y);
            pb.us[i*4+2] = f2bf(bv.z); pb.us[i*4+3] = f2bf(bv.w);
        }
        *(uint4*)(lA)     = pa.q[0];
        *(uint4*)(lA + 8) = pa.q[1];
        *(uint4*)(lB)     = pb.q[0];
        *(uint4*)(lB + 8) = pb.q[1];
        __syncthreads();

        short8 af[4], bf[4];
#pragma unroll
        for (int m = 0; m < 4; ++m)
            af[m] = *(const short8*)&As[wr * 64 + m * 16 + lrow][lgrp * 8];
#pragma unroll
        for (int n = 0; n < 4; ++n)
            bf[n] = *(const short8*)&Bs[wc * 64 + n * 16 + lrow][lgrp * 8];
#pragma unroll
        for (int m = 0; m < 4; ++m)
#pragma unroll
            for (int n = 0; n < 4; ++n)
                acc[m][n] = __builtin_amdgcn_mfma_f32_16x16x32_bf16(af[m], bf[n], acc[m][n], 0, 0, 0);
    }

    const int b = mt >> 3;
    float vv[4], ps[4];
#pragma unroll
    for (int n = 0; n < 4; ++n) {
        int col = nt * 128 + wc * 64 + n * 16 + lrow;
        vv[n] = v[col];
        ps[n] = proj_s[b * H_ + col];
    }
    float rs[4][4];
#pragma unroll
    for (int m = 0; m < 4; ++m) {
#pragma unroll
        for (int j = 0; j < 4; ++j) {
            float s = 0.0f;
#pragma unroll
            for (int n = 0; n < 4; ++n)
                s = fmaf(tanh_fast(acc[m][n][j] + ps[n]), vv[n], s);
            s += __shfl_xor(s, 1, 64);
            s += __shfl_xor(s, 2, 64);
            s += __shfl_xor(s, 4, 64);
            s += __shfl_xor(s, 8, 64);
            rs[m][j] = s;
        }
    }
    if (lrow == 0) {
#pragma unroll
        for (int m = 0; m < 4; ++m)
#pragma unroll
            for (int j = 0; j < 4; ++j)
                sums[wr * 64 + m * 16 + lgrp * 4 + j][wc] = rs[m][j];
    }
    __syncthreads();
    if (t < 128)
        scores_part[(size_t)nt * M_ + mt * 128 + t] = sums[t][0] + sums[t][1];
}

// ---------------------------------------------------------------------------
// K3: softmax over S per batch row (np N-tile partials)
// ---------------------------------------------------------------------------
__global__ void softmax_kernel(const float* __restrict__ scores_part,
                               const int* __restrict__ mask,
                               float* __restrict__ weights, int np) {
    const int b = blockIdx.x, t = threadIdx.x;
    __shared__ float red[8];
    float sc[4];
#pragma unroll
    for (int i = 0; i < 4; ++i) {
        int s = t + i * 256;
        float x = 0.0f;
        for (int p = 0; p < np; ++p)
            x += scores_part[(size_t)p * M_ + b * S_ + s];
        if (mask[b * S_ + s] == 0) x = -INFINITY;
        sc[i] = x;
    }
    float mx = fmaxf(fmaxf(sc[0], sc[1]), fmaxf(sc[2], sc[3]));
#pragma unroll
    for (int m = 32; m >= 1; m >>= 1) mx = fmaxf(mx, __shfl_xor(mx, m, 64));
    if ((t & 63) == 0) red[t >> 6] = mx;
    __syncthreads();
    mx = fmaxf(fmaxf(red[0], red[1]), fmaxf(red[2], red[3]));

    float e[4]; float sum = 0.0f;
#pragma unroll
    for (int i = 0; i < 4; ++i) { e[i] = __expf(sc[i] - mx); sum += e[i]; }
#pragma unroll
    for (int m = 32; m >= 1; m >>= 1) sum += __shfl_xor(sum, m, 64);
    if ((t & 63) == 0) red[4 + (t >> 6)] = sum;
    __syncthreads();
    sum = red[4] + red[5] + red[6] + red[7];
    float inv = 1.0f / sum;
#pragma unroll
    for (int i = 0; i < 4; ++i)
        weights[b * S_ + t + i * 256] = e[i] * inv;
}

// ---------------------------------------------------------------------------
// K4 fast: context partials reading bf16 enc. grid = 1024 = b(64) x sc(16),
// 128 threads; thread owns 8 h over 64 s-rows.
// ---------------------------------------------------------------------------
__global__ void context_part_bf16_kernel(const unsigned short* __restrict__ encb,
                                         const float* __restrict__ weights,
                                         float* __restrict__ ctx_part) {
    const int b = blockIdx.x >> 4;
    const int sc = blockIdx.x & 15;
    const int t = threadIdx.x;   // 0..127
    __shared__ float wv[64];
    if (t < 64) wv[t] = weights[b * S_ + sc * 64 + t];
    __syncthreads();
    const short8* e8 = (const short8*)(encb + (size_t)(b * S_ + sc * 64) * H_) + t;
    float a[8] = {};
#pragma unroll 4
    for (int i = 0; i < 64; ++i) {
        short8 ev = e8[(size_t)i * 128];
        float w = wv[i];
#pragma unroll
        for (int j = 0; j < 8; ++j)
            a[j] = fmaf(w, bf2f((unsigned short)ev[j]), a[j]);
    }
    float* dst = ctx_part + (size_t)sc * M_ + b * H_ + t * 8;
    float4 o0; o0.x = a[0]; o0.y = a[1]; o0.z = a[2]; o0.w = a[3];
    float4 o1; o1.x = a[4]; o1.y = a[5]; o1.z = a[6]; o1.w = a[7];
    *(float4*)dst = o0;
    *(float4*)(dst + 4) = o1;
}

__global__ void context_part_kernel(const float* __restrict__ enc,
                                    const float* __restrict__ weights,
                                    float* __restrict__ ctx_part) {
    const int b = blockIdx.x >> 4;
    const int sc = blockIdx.x & 15;
    const int t = threadIdx.x;
    __shared__ float wv[64];
    if (t < 64) wv[t] = weights[b * S_ + sc * 64 + t];
    __syncthreads();
    const float4* e4 = (const float4*)(enc + (size_t)(b * S_ + sc * 64) * H_) + t;
    float ax = 0.f, ay = 0.f, az = 0.f, aw = 0.f;
#pragma unroll 4
    for (int i = 0; i < 64; ++i) {
        float4 ev = e4[i * 256];
        float wgt = wv[i];
        ax = fmaf(wgt, ev.x, ax);
        ay = fmaf(wgt, ev.y, ay);
        az = fmaf(wgt, ev.z, az);
        aw = fmaf(wgt, ev.w, aw);
    }
    float4 o; o.x = ax; o.y = ay; o.z = az; o.w = aw;
    *((float4*)(ctx_part + (size_t)sc * M_ + b * H_) + t) = o;
}

__global__ void ctx_reduce_kernel(const float* __restrict__ ctx_part,
                                  float* __restrict__ ctx, int np) {
    int idx = blockIdx.x * 256 + threadIdx.x;
    float s = 0.0f;
    for (int p = 0; p < np; ++p) s += ctx_part[(size_t)p * M_ + idx];
    ctx[idx] = s;
}

extern "C" void kernel_launch(void* const* d_in, const int* in_sizes, int n_in,
                              void* d_out, int out_size, void* d_ws, size_t ws_size,
                              hipStream_t stream) {
    const float* dec  = (const float*)d_in[0];   // [B,H]
    const float* enc  = (const float*)d_in[1];   // [B,S,H]
    const int*   mask = (const int*)d_in[2];     // [B,S]
    const float* Ws   = (const float*)d_in[3];   // [H,H]
    const float* Wh   = (const float*)d_in[4];   // [H,H]
    const float* v    = (const float*)d_in[5];   // [H]

    float* out = (float*)d_out;          // [0:65536] context, [65536:131072] weights

    float* proj_s      = (float*)d_ws;                   // 65536 f32
    float* proj_part   = proj_s + M_;                    // 16 * 65536 f32
    float* scores_part = proj_part + 16 * (size_t)M_;    // 8 * 65536 f32
    float* ctx_part    = scores_part + 8 * (size_t)M_;   // 32 * 65536 f32 (16 used)
    unsigned short* encb = (unsigned short*)(ctx_part + 32 * (size_t)M_);  // 64M bf16
    unsigned short* Whb  = encb + (size_t)B_ * S_ * H_;                    // 1M bf16

    const size_t need_small = 4ull * (1 + 16 + 8 + 32) * M_;
    const size_t need_big   = need_small + 2ull * ((size_t)B_ * S_ * H_ + (size_t)H_ * H_);

    proj_s_part_kernel<<<256, 256, 0, stream>>>(dec, Ws, proj_part);
    proj_red_kernel<<<256, 256, 0, stream>>>(proj_part, proj_s);

    if (ws_size >= need_big) {
        cvt2_bf16_kernel<<<2048, 256, 0, stream>>>(enc, encb, B_ * S_ * H_ / 8,
                                                   Wh, Whb, H_ * H_ / 8);
        fused_scores_p4_kernel<<<1024, 512, 0, stream>>>(encb, Whb, proj_s, v, scores_part);
        softmax_kernel<<<64, 256, 0, stream>>>(scores_part, mask, out + M_, 4);
        context_part_bf16_kernel<<<1024, 128, 0, stream>>>(encb, out + M_, ctx_part);
        ctx_reduce_kernel<<<256, 256, 0, stream>>>(ctx_part, out, 16);
    } else {
        fused_scores_kernel<<<4096, 256, 0, stream>>>(enc, Wh, proj_s, v, scores_part);
        softmax_kernel<<<64, 256, 0, stream>>>(scores_part, mask, out + M_, 8);
        context_part_kernel<<<1024, 256, 0, stream>>>(enc, out + M_, ctx_part);
        ctx_reduce_kernel<<<256, 256, 0, stream>>>(ctx_part, out, 16);
    }
}